// Round 8
// baseline (480.526 us; speedup 1.0000x reference)
//
#include <hip/hip_runtime.h>
#include <hip/hip_bf16.h>

typedef float f32x4 __attribute__((ext_vector_type(4)));
typedef short bf16x8 __attribute__((ext_vector_type(8)));
typedef unsigned short ushort_t;

// ---------- bf16 helpers (RNE) ----------
__device__ __forceinline__ ushort_t f2bf(float f) {
    union { float f; unsigned u; } v; v.f = f;
    unsigned r = v.u + 0x7fffu + ((v.u >> 16) & 1u);
    return (ushort_t)(r >> 16);
}
__device__ __forceinline__ float bf2f(ushort_t h) {
    union { unsigned u; float f; } v; v.u = ((unsigned)h) << 16;
    return v.f;
}

// ---------- async global->LDS 16B/lane (wave-uniform LDS base + lane*16) ----------
__device__ __forceinline__ void async16(ushort_t* lds, const ushort_t* g) {
    __builtin_amdgcn_global_load_lds(
        (const __attribute__((address_space(1))) unsigned int*)g,
        (__attribute__((address_space(3))) unsigned int*)lds, 16, 0, 0);
}

// ---------- ONE prep dispatch: cast 4 weight mats + pack both Wsr ----------
// blocks [0,512): wq..wp cast (131072 threads x 8 elems)
// blocks [512,2560): Wsr pack, float4 read + 4 coalesced tap-segment writes
__global__ __launch_bounds__(256) void prep_w_kernel(const float* __restrict__ Wq,
                                                     const float* __restrict__ Wk,
                                                     const float* __restrict__ Wv,
                                                     const float* __restrict__ Wp,
                                                     ushort_t* __restrict__ wdst,
                                                     const float* __restrict__ w0,
                                                     const float* __restrict__ w1,
                                                     ushort_t* __restrict__ pout) {
    int bid = blockIdx.x;
    if (bid < 512) {
        long idx = (long)bid * 256 + threadIdx.x;          // 131072 threads
        int sel = (int)(idx >> 15);
        const float* s = sel == 0 ? Wq : sel == 1 ? Wk : sel == 2 ? Wv : Wp;
        long off = (idx & 32767) * 8;
        float4 a = *(const float4*)(s + off);
        float4 b = *(const float4*)(s + off + 4);
        ushort_t o[8];
        o[0]=f2bf(a.x); o[1]=f2bf(a.y); o[2]=f2bf(a.z); o[3]=f2bf(a.w);
        o[4]=f2bf(b.x); o[5]=f2bf(b.y); o[6]=f2bf(b.z); o[7]=f2bf(b.w);
        *(bf16x8*)(wdst + (long)sel * 262144 + off) = *(bf16x8*)o;
    } else {
        int idx = (bid - 512) * 256 + threadIdx.x;          // 524288 total
        int sel = idx >> 18;
        const float* w = sel ? w1 : w0;
        int li = idx & 262143;
        int c = li >> 9, ci = li & 511;
        float4 t = *(const float4*)(w + c * 2048 + ci * 4);   // taps 0..3
        ushort_t* ob = pout + sel * 1048576 + c * 2048 + ci;
        ob[0]    = f2bf(t.x);
        ob[512]  = f2bf(t.y);
        ob[1024] = f2bf(t.z);
        ob[1536] = f2bf(t.w);
    }
}

// ---------- multi-job 128x128 bf16 MFMA GEMM: C = (A[M,K]*B[512,K]^T + bias)*oscale ----
// Jobs {M,K,gather,oscale,afp32} in one flat-grid dispatch (backfill idle CUs).
// afp32=1: A is raw fp32 input — staged via reg (float4 x2 -> RNE cvt -> ds_write),
//          eliminating the separate 192MB cast pass entirely (conversion is free in
//          the staging lane; bit-identical RNE to the old cast kernel).
// afp32=0: A bf16 — staged via global_load_lds width=16. B always gload_lds.
// XCD-grouped decode: 4 col-blocks sharing a row-panel differ by 8/16/24 in bid ->
// same XCD (bid%8, m09/T1) -> A-panel L2-hits instead of 4x HBM re-fetch.
// LDS LINEAR [128][64] (gload_lds contract). omode 0: bf16 [M,512]; 1: fp32;
// 2: bf16 transposed vT[B,8,64,1024].
struct GemmJob {
    const void* A;
    const ushort_t* Bw;
    const float* bias;
    void* C;
    int omode;
    int M;
    int K;
    int gather;
    float oscale;
    int afp32;
};

__global__ __launch_bounds__(256) void gemm_multi(GemmJob j0, GemmJob j1, GemmJob j2,
                                                  int nb0, int nb1) {
    __shared__ __align__(16) ushort_t As[128][64];
    __shared__ __align__(16) ushort_t Bs[128][64];
    const int bid = blockIdx.x;
    GemmJob j;
    int local;
    if (bid < nb0)            { j = j0; local = bid; }
    else if (bid < nb0 + nb1) { j = j1; local = bid - nb0; }
    else                      { j = j2; local = bid - nb0 - nb1; }

    const int tid  = threadIdx.x;
    // XCD-grouped decode: row = (local&7) | ((local>>5)<<3), col = (local>>3)&3
    const int row0 = (((local & 7) | ((local >> 5) << 3))) * 128;
    const int col0 = ((local >> 3) & 3) * 128;
    const int wave = tid >> 6, lane = tid & 63;
    const int rw = wave >> 1, cw = wave & 1;
    const int l15 = lane & 15, l4 = lane >> 4;
    const int srow = wave * 8 + (lane >> 3);     // staging row within 32-row group
    const int sc8  = (lane & 7) * 8;             // staging col (elems)
    const int K = j.K;

    f32x4 acc[4][4] = {};

    for (int k0 = 0; k0 < K; k0 += 64) {
        __syncthreads();                         // prev tile's reads done
#pragma unroll
        for (int p = 0; p < 4; ++p) {
            int r = p * 32 + srow;
            long aoff;
            if (j.gather) {
                int gr = row0 + r;
                int b = gr >> 10, m = gr & 1023;
                int mh = m >> 5, mw = m & 31;
                int tap = k0 >> 9;
                int kh = tap >> 1, kw = tap & 1;
                aoff = ((long)(b * 4096 + (2 * mh + kh) * 64 + (2 * mw + kw))) * 512
                       + (k0 & 511) + sc8;
            } else {
                aoff = (long)(row0 + r) * K + k0 + sc8;
            }
            if (j.afp32) {
                const float* ga = (const float*)j.A + aoff;
                float4 a0 = *(const float4*)ga;
                float4 a1 = *(const float4*)(ga + 4);
                ushort_t o[8];
                o[0]=f2bf(a0.x); o[1]=f2bf(a0.y); o[2]=f2bf(a0.z); o[3]=f2bf(a0.w);
                o[4]=f2bf(a1.x); o[5]=f2bf(a1.y); o[6]=f2bf(a1.z); o[7]=f2bf(a1.w);
                *(bf16x8*)&As[r][sc8] = *(bf16x8*)o;
            } else {
                async16(&As[p * 32 + wave * 8][0], (const ushort_t*)j.A + aoff);
            }
            async16(&Bs[p * 32 + wave * 8][0],
                    j.Bw + (long)(col0 + r) * K + k0 + sc8);
        }
        __syncthreads();                         // ds_write lgkmcnt + gload vmcnt drained
#pragma unroll
        for (int ks = 0; ks < 2; ++ks) {
            bf16x8 af[4], bfr[4];
#pragma unroll
            for (int i = 0; i < 4; ++i)
                af[i] = *(const bf16x8*)&As[rw * 64 + i * 16 + l15][ks * 32 + l4 * 8];
#pragma unroll
            for (int jj = 0; jj < 4; ++jj)
                bfr[jj] = *(const bf16x8*)&Bs[cw * 64 + jj * 16 + l15][ks * 32 + l4 * 8];
#pragma unroll
            for (int i = 0; i < 4; ++i)
#pragma unroll
                for (int jj = 0; jj < 4; ++jj)
                    acc[i][jj] = __builtin_amdgcn_mfma_f32_16x16x32_bf16(af[i], bfr[jj],
                                                                         acc[i][jj], 0, 0, 0);
        }
    }
    // epilogue: C/D layout col=lane&15, row=(lane>>4)*4+reg  [m89-verified]
#pragma unroll
    for (int i = 0; i < 4; ++i) {
#pragma unroll
        for (int jj = 0; jj < 4; ++jj) {
            int col = col0 + cw * 64 + jj * 16 + l15;
            float bv = j.bias[col];
#pragma unroll
            for (int r = 0; r < 4; ++r) {
                int row = row0 + rw * 64 + i * 16 + l4 * 4 + r;
                float v = (acc[i][jj][r] + bv) * j.oscale;
                if (j.omode == 0) {
                    ((ushort_t*)j.C)[(long)row * 512 + col] = f2bf(v);
                } else if (j.omode == 1) {
                    ((float*)j.C)[(long)row * 512 + col] = v;
                } else {
                    int b = row >> 10, m = row & 1023;
                    int hh = col >> 6, dd = col & 63;
                    ((ushort_t*)j.C)[(((long)(b * 8 + hh) * 64 + dd) << 10) + m] = f2bf(v);
                }
            }
        }
    }
}

// ---------- in-place LayerNorm over rows of 512 (bf16), wave per row ----------
// rows 0..8191 use (g0,be0); rows 8192..16383 use (g1,be1)  (convk||convv contiguous)
__global__ __launch_bounds__(256) void ln_kernel(ushort_t* __restrict__ data,
                                                 const float* __restrict__ g0,
                                                 const float* __restrict__ be0,
                                                 const float* __restrict__ g1,
                                                 const float* __restrict__ be1) {
    int wave = threadIdx.x >> 6, lane = threadIdx.x & 63;
    long row = (long)blockIdx.x * 4 + wave;
    const float* g  = row < 8192 ? g0 : g1;
    const float* be = row < 8192 ? be0 : be1;
    ushort_t* p = data + row * 512 + lane * 8;
    bf16x8 raw = *(bf16x8*)p;
    ushort_t* rp = (ushort_t*)&raw;
    float v[8], s = 0.f, s2 = 0.f;
#pragma unroll
    for (int j = 0; j < 8; ++j) { v[j] = bf2f(rp[j]); s += v[j]; s2 += v[j] * v[j]; }
#pragma unroll
    for (int d = 1; d < 64; d <<= 1) { s += __shfl_xor(s, d); s2 += __shfl_xor(s2, d); }
    float mu  = s * (1.f / 512.f);
    float var = s2 * (1.f / 512.f) - mu * mu;
    float rs  = rsqrtf(var + 1e-5f);
    ushort_t o[8];
#pragma unroll
    for (int j = 0; j < 8; ++j) {
        int c = lane * 8 + j;
        o[j] = f2bf((v[j] - mu) * rs * g[c] + be[c]);
    }
    *(bf16x8*)p = *(bf16x8*)o;
}

// ---------- flash attention v7 (R7-exact, PASSED): Q pre-scaled by EC in q-proj ----
// Block = (b, head, 128 q-rows); wave owns 32 q-rows (2 n-blocks), sharing each
// K-fragment and V-fragment across both. Q fragments in registers. P = exp2(S)
// directly. P packed by HW v_cvt_pk_bf16_f32. l = sum_m P via ones-B MFMA.
// NOTE: T14 async-split staging FAILED here (absmax 0.13, R2) — do not re-add
// without asm-level verification of the wait placement.
__global__ __launch_bounds__(256, 3) void attn_kernel(const ushort_t* __restrict__ q,
                                                      const ushort_t* __restrict__ k,
                                                      const ushort_t* __restrict__ vt,
                                                      ushort_t* __restrict__ o) {
    __shared__ __align__(16) ushort_t Ks[128][72];
    __shared__ __align__(16) ushort_t Vs[64][136];   // V^T: [d][m]

    const int tid = threadIdx.x;
    const int wave = tid >> 6, lane = tid & 63;
    const int l15 = lane & 15, l4 = lane >> 4;
    const int n0 = blockIdx.x * 128;
    const int hh = blockIdx.y;
    const int b  = blockIdx.z;

    // Q fragments: wave's q-rows are n0 + wave*32 + nb*16 + l15 (pre-scaled bf16)
    bf16x8 bq[2][2];
#pragma unroll
    for (int nb = 0; nb < 2; ++nb)
#pragma unroll
        for (int ks = 0; ks < 2; ++ks)
            bq[nb][ks] = *(const bf16x8*)(
                q + (long)(b * 4096 + n0 + wave * 32 + nb * 16 + l15) * 512
                  + hh * 64 + ks * 32 + l4 * 8);

    f32x4 oacc[2][4] = {};
    f32x4 lacc[2] = {};
    union { bf16x8 v8; unsigned u[4]; } ones;
    ones.u[0] = ones.u[1] = ones.u[2] = ones.u[3] = 0x3F803F80u;

    for (int c = 0; c < 8; ++c) {
        const int m0 = c * 128;
        __syncthreads();                    // previous chunk's LDS reads done
#pragma unroll
        for (int p = 0; p < 4; ++p) {       // K chunk [128 m][64 d]
            int qi = p * 256 + tid;
            int r = qi >> 3, c8 = (qi & 7) * 8;
            bf16x8 v = *(const bf16x8*)(k + (((long)(b * 1024 + m0 + r) * 8 + hh) << 6) + c8);
            *(bf16x8*)&Ks[r][c8] = v;
        }
#pragma unroll
        for (int p = 0; p < 4; ++p) {       // V^T chunk [64 d][128 m]
            int qi = p * 256 + tid;
            int dd = qi >> 4, c8 = (qi & 15) * 8;
            bf16x8 v = *(const bf16x8*)(vt + (((long)(b * 8 + hh) * 64 + dd) << 10) + m0 + c8);
            *(bf16x8*)&Vs[dd][c8] = v;
        }
        __syncthreads();                    // staging visible

        // S^T = K·Q^T: each K-fragment feeds both n-blocks
        f32x4 s[2][8] = {};
        __builtin_amdgcn_s_setprio(1);
#pragma unroll
        for (int ks = 0; ks < 2; ++ks) {
#pragma unroll
            for (int i = 0; i < 8; ++i) {
                bf16x8 ak = *(const bf16x8*)&Ks[i * 16 + l15][ks * 32 + l4 * 8];
                s[0][i] = __builtin_amdgcn_mfma_f32_16x16x32_bf16(ak, bq[0][ks], s[0][i], 0, 0, 0);
                s[1][i] = __builtin_amdgcn_mfma_f32_16x16x32_bf16(ak, bq[1][ks], s[1][i], 0, 0, 0);
            }
        }
        __builtin_amdgcn_s_setprio(0);

        // P = exp2(S) (Q pre-scaled), packed to bf16 pairs by HW cvt_pk
        unsigned pk[2][8][2];
#pragma unroll
        for (int nb = 0; nb < 2; ++nb)
#pragma unroll
            for (int i = 0; i < 8; ++i) {
                float e0 = __builtin_amdgcn_exp2f(s[nb][i][0]);
                float e1 = __builtin_amdgcn_exp2f(s[nb][i][1]);
                float e2 = __builtin_amdgcn_exp2f(s[nb][i][2]);
                float e3 = __builtin_amdgcn_exp2f(s[nb][i][3]);
                asm("v_cvt_pk_bf16_f32 %0, %1, %2" : "=v"(pk[nb][i][0]) : "v"(e0), "v"(e1));
                asm("v_cvt_pk_bf16_f32 %0, %1, %2" : "=v"(pk[nb][i][1]) : "v"(e2), "v"(e3));
            }

        // O += P·V ; l += P·1  (permuted k-slots: slot (l4,j) carries
        // m = (2*mb + (j>>2))*16 + l4*4 + (j&3) — lane's own pk regs = A-frag).
        __builtin_amdgcn_s_setprio(1);
#pragma unroll
        for (int mb = 0; mb < 4; ++mb) {
            union { bf16x8 v8; unsigned long long h[2]; } bfr[4];
#pragma unroll
            for (int db = 0; db < 4; ++db) {
                bfr[db].h[0] = *(const unsigned long long*)&Vs[db * 16 + l15][mb * 32 + l4 * 4];
                bfr[db].h[1] = *(const unsigned long long*)&Vs[db * 16 + l15][mb * 32 + 16 + l4 * 4];
            }
#pragma unroll
            for (int nb = 0; nb < 2; ++nb) {
                union { bf16x8 v8; unsigned u32v[4]; } af;
                af.u32v[0] = pk[nb][2 * mb][0];
                af.u32v[1] = pk[nb][2 * mb][1];
                af.u32v[2] = pk[nb][2 * mb + 1][0];
                af.u32v[3] = pk[nb][2 * mb + 1][1];
                lacc[nb] = __builtin_amdgcn_mfma_f32_16x16x32_bf16(af.v8, ones.v8,
                                                                   lacc[nb], 0, 0, 0);
#pragma unroll
                for (int db = 0; db < 4; ++db)
                    oacc[nb][db] = __builtin_amdgcn_mfma_f32_16x16x32_bf16(af.v8, bfr[db].v8,
                                                                           oacc[nb][db], 0, 0, 0);
            }
        }
        __builtin_amdgcn_s_setprio(0);
    }

    // finalize: O /= l — lacc[nb][r] is l at n = wave*32 + nb*16 + l4*4 + r
#pragma unroll
    for (int nb = 0; nb < 2; ++nb)
#pragma unroll
        for (int r = 0; r < 4; ++r) {
            float inv = 1.f / lacc[nb][r];
            int n = wave * 32 + nb * 16 + l4 * 4 + r;
#pragma unroll
            for (int db = 0; db < 4; ++db) {
                int dd = db * 16 + l15;
                o[((long)(b * 4096 + n0 + n)) * 512 + hh * 64 + dd] = f2bf(oacc[nb][db][r] * inv);
            }
        }
}

extern "C" void kernel_launch(void* const* d_in, const int* in_sizes, int n_in,
                              void* d_out, int out_size, void* d_ws, size_t ws_size,
                              hipStream_t stream) {
    const float* x    = (const float*)d_in[0];
    const float* ctx  = (const float*)d_in[1];
    const float* Wq   = (const float*)d_in[2];
    const float* bq   = (const float*)d_in[3];
    const float* Wk   = (const float*)d_in[4];
    const float* bk   = (const float*)d_in[5];
    const float* Wv   = (const float*)d_in[6];
    const float* bv   = (const float*)d_in[7];
    const float* Wp   = (const float*)d_in[8];
    const float* bp   = (const float*)d_in[9];
    const float* Wsrk = (const float*)d_in[10];
    const float* bsrk = (const float*)d_in[11];
    const float* Wsrv = (const float*)d_in[12];
    const float* bsrv = (const float*)d_in[13];
    const float* gk   = (const float*)d_in[14];
    const float* bek  = (const float*)d_in[15];
    const float* gv   = (const float*)d_in[16];
    const float* bev  = (const float*)d_in[17];

    // workspace layout (elems of bf16) — x_bf/ctx_bf regions retired (fp32 staged
    // directly in gemm); offsets kept stable for minimal diff.
    ushort_t* q_bf    = (ushort_t*)d_ws + 33554432;
    ushort_t* at_bf   = q_bf    + 16777216;
    ushort_t* k_bf    = at_bf   + 16777216;
    ushort_t* vt_bf   = k_bf    + 4194304;
    ushort_t* convk   = vt_bf   + 4194304;   // LN in-place -> ctx_k
    ushort_t* convv   = convk   + 4194304;   // LN in-place -> ctx_v (contiguous!)
    ushort_t* wq_bf   = convv   + 4194304;   // wq..wp contiguous
    ushort_t* wk_bf   = wq_bf   + 262144;
    ushort_t* wv_bf   = wk_bf   + 262144;
    ushort_t* wp_bf   = wv_bf   + 262144;
    ushort_t* wsrk_p  = wp_bf   + 262144;    // wsrk_p||wsrv_p contiguous
    ushort_t* wsrv_p  = wsrk_p  + 1048576;

    const float EC = 0.18033688011112042f;   // 0.125 * log2(e), folded into q-proj

    // 1) single prep dispatch: weight casts + Wsr packing
    prep_w_kernel<<<2560, 256, 0, stream>>>(Wq, Wk, Wv, Wp, wq_bf, Wsrk, Wsrv, wsrk_p);

    // 2) MERGED: conv-k + conv-v (gather, K=2048) + q-proj (K=512, pre-scaled by EC),
    //    all reading RAW FP32 inputs with in-staging RNE conversion (no cast pass).
    GemmJob jck = { ctx, wsrk_p, bsrk, convk, 0, 8192,  2048, 1, 1.0f, 1 };
    GemmJob jcv = { ctx, wsrv_p, bsrv, convv, 0, 8192,  2048, 1, 1.0f, 1 };
    GemmJob jq  = { x,   wq_bf,  bq,   q_bf,  0, 32768, 512,  0, EC,   1 };
    gemm_multi<<<1536, 256, 0, stream>>>(jck, jcv, jq, 256, 256);

    // 3) both LayerNorms in one dispatch (convk||convv contiguous)
    ln_kernel<<<4096, 256, 0, stream>>>(convk, gk, bek, gv, bev);

    // 4) k+v projections as dual-job (512 blocks, bf16 A via gload_lds)
    GemmJob jk  = { convk, wk_bf, bk, k_bf,  0, 8192, 512, 0, 1.0f, 0 };
    GemmJob jv  = { convv, wv_bf, bv, vt_bf, 2, 8192, 512, 0, 1.0f, 0 };
    gemm_multi<<<512, 256, 0, stream>>>(jk, jv, jv, 256, 256);

    // 5) attention: 128 q-rows/block, 2 n-blocks/wave (Q pre-scaled, exp2 direct)
    attn_kernel<<<dim3(32, 8, 8), 256, 0, stream>>>(q_bf, k_bf, vt_bf, at_bf);

    // 6) output projection -> fp32 d_out
    GemmJob jo  = { at_bf, wp_bf, bp, d_out, 1, 32768, 512, 0, 1.0f, 0 };
    gemm_multi<<<1024, 256, 0, stream>>>(jo, jo, jo, 1024, 0);
}

// Round 9
// 430.177 us; speedup vs baseline: 1.1170x; 1.1170x over previous
//
#include <hip/hip_runtime.h>
#include <hip/hip_bf16.h>

typedef float f32x4 __attribute__((ext_vector_type(4)));
typedef short bf16x8 __attribute__((ext_vector_type(8)));
typedef unsigned short ushort_t;

// ---------- bf16 helpers (RNE) ----------
__device__ __forceinline__ ushort_t f2bf(float f) {
    union { float f; unsigned u; } v; v.f = f;
    unsigned r = v.u + 0x7fffu + ((v.u >> 16) & 1u);
    return (ushort_t)(r >> 16);
}
__device__ __forceinline__ float bf2f(ushort_t h) {
    union { unsigned u; float f; } v; v.u = ((unsigned)h) << 16;
    return v.f;
}

// ---------- async global->LDS 16B/lane (wave-uniform LDS base + lane*16) ----------
__device__ __forceinline__ void async16(ushort_t* lds, const ushort_t* g) {
    __builtin_amdgcn_global_load_lds(
        (const __attribute__((address_space(1))) unsigned int*)g,
        (__attribute__((address_space(3))) unsigned int*)lds, 16, 0, 0);
}

// ---------- ONE prep dispatch: input casts + weight casts + Wsr pack ----------
// blocks [0,16384):      cast x||ctx fp32 -> bf16 (x_bf||ctx_bf contiguous)
// blocks [16384,16896):  cast Wq..Wp (131072 threads x 8 elems)
// blocks [16896,18944):  Wsr pack, float4 read + 4 coalesced tap-segment writes
// R8 LESSON: do NOT fold the input cast into GEMM staging — synchronous fp32
// reg-staging puts HBM latency inside the barrier window (88->188 us regression).
// The separate cast pass + global_load_lds A is the proven-fast dataflow (R7).
__global__ __launch_bounds__(256) void prep_all_kernel(const float* __restrict__ x,
                                                       const float* __restrict__ ctx,
                                                       ushort_t* __restrict__ xdst,
                                                       const float* __restrict__ Wq,
                                                       const float* __restrict__ Wk,
                                                       const float* __restrict__ Wv,
                                                       const float* __restrict__ Wp,
                                                       ushort_t* __restrict__ wdst,
                                                       const float* __restrict__ w0,
                                                       const float* __restrict__ w1,
                                                       ushort_t* __restrict__ pout) {
    int bid = blockIdx.x;
    if (bid < 16384) {
        long idx = (long)bid * 256 + threadIdx.x;   // 4194304 threads
        int sel = (int)(idx >> 21);
        const float* s = sel ? ctx : x;
        long off = (idx & 2097151) * 8;
        float4 a = *(const float4*)(s + off);
        float4 b = *(const float4*)(s + off + 4);
        ushort_t o[8];
        o[0]=f2bf(a.x); o[1]=f2bf(a.y); o[2]=f2bf(a.z); o[3]=f2bf(a.w);
        o[4]=f2bf(b.x); o[5]=f2bf(b.y); o[6]=f2bf(b.z); o[7]=f2bf(b.w);
        *(bf16x8*)(xdst + (long)sel * 16777216 + off) = *(bf16x8*)o;
    } else if (bid < 16896) {
        long idx = (long)(bid - 16384) * 256 + threadIdx.x;   // 131072 threads
        int sel = (int)(idx >> 15);
        const float* s = sel == 0 ? Wq : sel == 1 ? Wk : sel == 2 ? Wv : Wp;
        long off = (idx & 32767) * 8;
        float4 a = *(const float4*)(s + off);
        float4 b = *(const float4*)(s + off + 4);
        ushort_t o[8];
        o[0]=f2bf(a.x); o[1]=f2bf(a.y); o[2]=f2bf(a.z); o[3]=f2bf(a.w);
        o[4]=f2bf(b.x); o[5]=f2bf(b.y); o[6]=f2bf(b.z); o[7]=f2bf(b.w);
        *(bf16x8*)(wdst + (long)sel * 262144 + off) = *(bf16x8*)o;
    } else {
        int idx = (bid - 16896) * 256 + threadIdx.x;   // 524288 total
        int sel = idx >> 18;
        const float* w = sel ? w1 : w0;
        int li = idx & 262143;
        int c = li >> 9, ci = li & 511;
        float4 t = *(const float4*)(w + c * 2048 + ci * 4);   // taps 0..3
        ushort_t* ob = pout + sel * 1048576 + c * 2048 + ci;
        ob[0]    = f2bf(t.x);
        ob[512]  = f2bf(t.y);
        ob[1024] = f2bf(t.z);
        ob[1536] = f2bf(t.w);
    }
}

// ---------- multi-job 128x128 bf16 MFMA GEMM: C = (A[M,K]*B[512,K]^T + bias)*oscale ----
// Jobs {M,K,gather,oscale} in one flat-grid dispatch (backfill idle CUs).
// XCD-grouped decode: 4 col-blocks sharing a row-panel differ by 8/16/24 in bid ->
// same XCD (bid%8, m09/T1) -> A-panel L2-hits instead of 4x HBM re-fetch.
// Staging via global_load_lds width=16 for BOTH A and B (R8 lesson: sync
// reg-staging regresses 2.1x). LDS LINEAR [128][64] (gload_lds contract).
// omode 0: bf16 [M,512]; 1: fp32; 2: bf16 transposed vT[B,8,64,1024].
struct GemmJob {
    const ushort_t* A;
    const ushort_t* Bw;
    const float* bias;
    void* C;
    int omode;
    int M;
    int K;
    int gather;
    float oscale;
};

__global__ __launch_bounds__(256) void gemm_multi(GemmJob j0, GemmJob j1, GemmJob j2,
                                                  int nb0, int nb1) {
    __shared__ __align__(16) ushort_t As[128][64];
    __shared__ __align__(16) ushort_t Bs[128][64];
    const int bid = blockIdx.x;
    GemmJob j;
    int local;
    if (bid < nb0)            { j = j0; local = bid; }
    else if (bid < nb0 + nb1) { j = j1; local = bid - nb0; }
    else                      { j = j2; local = bid - nb0 - nb1; }

    const int tid  = threadIdx.x;
    // XCD-grouped decode: row = (local&7) | ((local>>5)<<3), col = (local>>3)&3
    const int row0 = (((local & 7) | ((local >> 5) << 3))) * 128;
    const int col0 = ((local >> 3) & 3) * 128;
    const int wave = tid >> 6, lane = tid & 63;
    const int rw = wave >> 1, cw = wave & 1;
    const int l15 = lane & 15, l4 = lane >> 4;
    const int srow = wave * 8 + (lane >> 3);     // staging row within 32-row group
    const int sc8  = (lane & 7) * 8;             // staging col (elems)
    const int K = j.K;

    f32x4 acc[4][4] = {};

    for (int k0 = 0; k0 < K; k0 += 64) {
        __syncthreads();                         // prev tile's reads done
#pragma unroll
        for (int p = 0; p < 4; ++p) {
            int r = p * 32 + srow;
            const ushort_t* ga;
            if (j.gather) {
                int gr = row0 + r;
                int b = gr >> 10, m = gr & 1023;
                int mh = m >> 5, mw = m & 31;
                int tap = k0 >> 9;
                int kh = tap >> 1, kw = tap & 1;
                ga = j.A + ((long)(b * 4096 + (2 * mh + kh) * 64 + (2 * mw + kw))) * 512
                         + (k0 & 511) + sc8;
            } else {
                ga = j.A + (long)(row0 + r) * K + k0 + sc8;
            }
            async16(&As[p * 32 + wave * 8][0], ga);
            async16(&Bs[p * 32 + wave * 8][0],
                    j.Bw + (long)(col0 + r) * K + k0 + sc8);
        }
        __syncthreads();                         // vmcnt(0) drained by compiler
#pragma unroll
        for (int ks = 0; ks < 2; ++ks) {
            bf16x8 af[4], bfr[4];
#pragma unroll
            for (int i = 0; i < 4; ++i)
                af[i] = *(const bf16x8*)&As[rw * 64 + i * 16 + l15][ks * 32 + l4 * 8];
#pragma unroll
            for (int jj = 0; jj < 4; ++jj)
                bfr[jj] = *(const bf16x8*)&Bs[cw * 64 + jj * 16 + l15][ks * 32 + l4 * 8];
#pragma unroll
            for (int i = 0; i < 4; ++i)
#pragma unroll
                for (int jj = 0; jj < 4; ++jj)
                    acc[i][jj] = __builtin_amdgcn_mfma_f32_16x16x32_bf16(af[i], bfr[jj],
                                                                         acc[i][jj], 0, 0, 0);
        }
    }
    // epilogue: C/D layout col=lane&15, row=(lane>>4)*4+reg  [m89-verified]
#pragma unroll
    for (int i = 0; i < 4; ++i) {
#pragma unroll
        for (int jj = 0; jj < 4; ++jj) {
            int col = col0 + cw * 64 + jj * 16 + l15;
            float bv = j.bias[col];
#pragma unroll
            for (int r = 0; r < 4; ++r) {
                int row = row0 + rw * 64 + i * 16 + l4 * 4 + r;
                float v = (acc[i][jj][r] + bv) * j.oscale;
                if (j.omode == 0) {
                    ((ushort_t*)j.C)[(long)row * 512 + col] = f2bf(v);
                } else if (j.omode == 1) {
                    ((float*)j.C)[(long)row * 512 + col] = v;
                } else {
                    int b = row >> 10, m = row & 1023;
                    int hh = col >> 6, dd = col & 63;
                    ((ushort_t*)j.C)[(((long)(b * 8 + hh) * 64 + dd) << 10) + m] = f2bf(v);
                }
            }
        }
    }
}

// ---------- in-place LayerNorm over rows of 512 (bf16), wave per row ----------
// rows 0..8191 use (g0,be0); rows 8192..16383 use (g1,be1)  (convk||convv contiguous)
__global__ __launch_bounds__(256) void ln_kernel(ushort_t* __restrict__ data,
                                                 const float* __restrict__ g0,
                                                 const float* __restrict__ be0,
                                                 const float* __restrict__ g1,
                                                 const float* __restrict__ be1) {
    int wave = threadIdx.x >> 6, lane = threadIdx.x & 63;
    long row = (long)blockIdx.x * 4 + wave;
    const float* g  = row < 8192 ? g0 : g1;
    const float* be = row < 8192 ? be0 : be1;
    ushort_t* p = data + row * 512 + lane * 8;
    bf16x8 raw = *(bf16x8*)p;
    ushort_t* rp = (ushort_t*)&raw;
    float v[8], s = 0.f, s2 = 0.f;
#pragma unroll
    for (int j = 0; j < 8; ++j) { v[j] = bf2f(rp[j]); s += v[j]; s2 += v[j] * v[j]; }
#pragma unroll
    for (int d = 1; d < 64; d <<= 1) { s += __shfl_xor(s, d); s2 += __shfl_xor(s2, d); }
    float mu  = s * (1.f / 512.f);
    float var = s2 * (1.f / 512.f) - mu * mu;
    float rs  = rsqrtf(var + 1e-5f);
    ushort_t o[8];
#pragma unroll
    for (int j = 0; j < 8; ++j) {
        int c = lane * 8 + j;
        o[j] = f2bf((v[j] - mu) * rs * g[c] + be[c]);
    }
    *(bf16x8*)p = *(bf16x8*)o;
}

// ---------- flash attention v7 (R7-exact, PASSED): Q pre-scaled by EC in q-proj ----
// Block = (b, head, 128 q-rows); wave owns 32 q-rows (2 n-blocks), sharing each
// K-fragment and V-fragment across both. Q fragments in registers. P = exp2(S)
// directly. P packed by HW v_cvt_pk_bf16_f32. l = sum_m P via ones-B MFMA.
// NOTE: T14 async-split staging FAILED here (absmax 0.13, R2) — do not re-add
// without asm-level verification of the wait placement.
__global__ __launch_bounds__(256, 3) void attn_kernel(const ushort_t* __restrict__ q,
                                                      const ushort_t* __restrict__ k,
                                                      const ushort_t* __restrict__ vt,
                                                      ushort_t* __restrict__ o) {
    __shared__ __align__(16) ushort_t Ks[128][72];
    __shared__ __align__(16) ushort_t Vs[64][136];   // V^T: [d][m]

    const int tid = threadIdx.x;
    const int wave = tid >> 6, lane = tid & 63;
    const int l15 = lane & 15, l4 = lane >> 4;
    const int n0 = blockIdx.x * 128;
    const int hh = blockIdx.y;
    const int b  = blockIdx.z;

    // Q fragments: wave's q-rows are n0 + wave*32 + nb*16 + l15 (pre-scaled bf16)
    bf16x8 bq[2][2];
#pragma unroll
    for (int nb = 0; nb < 2; ++nb)
#pragma unroll
        for (int ks = 0; ks < 2; ++ks)
            bq[nb][ks] = *(const bf16x8*)(
                q + (long)(b * 4096 + n0 + wave * 32 + nb * 16 + l15) * 512
                  + hh * 64 + ks * 32 + l4 * 8);

    f32x4 oacc[2][4] = {};
    f32x4 lacc[2] = {};
    union { bf16x8 v8; unsigned u[4]; } ones;
    ones.u[0] = ones.u[1] = ones.u[2] = ones.u[3] = 0x3F803F80u;

    for (int c = 0; c < 8; ++c) {
        const int m0 = c * 128;
        __syncthreads();                    // previous chunk's LDS reads done
#pragma unroll
        for (int p = 0; p < 4; ++p) {       // K chunk [128 m][64 d]
            int qi = p * 256 + tid;
            int r = qi >> 3, c8 = (qi & 7) * 8;
            bf16x8 v = *(const bf16x8*)(k + (((long)(b * 1024 + m0 + r) * 8 + hh) << 6) + c8);
            *(bf16x8*)&Ks[r][c8] = v;
        }
#pragma unroll
        for (int p = 0; p < 4; ++p) {       // V^T chunk [64 d][128 m]
            int qi = p * 256 + tid;
            int dd = qi >> 4, c8 = (qi & 15) * 8;
            bf16x8 v = *(const bf16x8*)(vt + (((long)(b * 8 + hh) * 64 + dd) << 10) + m0 + c8);
            *(bf16x8*)&Vs[dd][c8] = v;
        }
        __syncthreads();                    // staging visible

        // S^T = K·Q^T: each K-fragment feeds both n-blocks
        f32x4 s[2][8] = {};
        __builtin_amdgcn_s_setprio(1);
#pragma unroll
        for (int ks = 0; ks < 2; ++ks) {
#pragma unroll
            for (int i = 0; i < 8; ++i) {
                bf16x8 ak = *(const bf16x8*)&Ks[i * 16 + l15][ks * 32 + l4 * 8];
                s[0][i] = __builtin_amdgcn_mfma_f32_16x16x32_bf16(ak, bq[0][ks], s[0][i], 0, 0, 0);
                s[1][i] = __builtin_amdgcn_mfma_f32_16x16x32_bf16(ak, bq[1][ks], s[1][i], 0, 0, 0);
            }
        }
        __builtin_amdgcn_s_setprio(0);

        // P = exp2(S) (Q pre-scaled), packed to bf16 pairs by HW cvt_pk
        unsigned pk[2][8][2];
#pragma unroll
        for (int nb = 0; nb < 2; ++nb)
#pragma unroll
            for (int i = 0; i < 8; ++i) {
                float e0 = __builtin_amdgcn_exp2f(s[nb][i][0]);
                float e1 = __builtin_amdgcn_exp2f(s[nb][i][1]);
                float e2 = __builtin_amdgcn_exp2f(s[nb][i][2]);
                float e3 = __builtin_amdgcn_exp2f(s[nb][i][3]);
                asm("v_cvt_pk_bf16_f32 %0, %1, %2" : "=v"(pk[nb][i][0]) : "v"(e0), "v"(e1));
                asm("v_cvt_pk_bf16_f32 %0, %1, %2" : "=v"(pk[nb][i][1]) : "v"(e2), "v"(e3));
            }

        // O += P·V ; l += P·1  (permuted k-slots: slot (l4,j) carries
        // m = (2*mb + (j>>2))*16 + l4*4 + (j&3) — lane's own pk regs = A-frag).
        __builtin_amdgcn_s_setprio(1);
#pragma unroll
        for (int mb = 0; mb < 4; ++mb) {
            union { bf16x8 v8; unsigned long long h[2]; } bfr[4];
#pragma unroll
            for (int db = 0; db < 4; ++db) {
                bfr[db].h[0] = *(const unsigned long long*)&Vs[db * 16 + l15][mb * 32 + l4 * 4];
                bfr[db].h[1] = *(const unsigned long long*)&Vs[db * 16 + l15][mb * 32 + 16 + l4 * 4];
            }
#pragma unroll
            for (int nb = 0; nb < 2; ++nb) {
                union { bf16x8 v8; unsigned u32v[4]; } af;
                af.u32v[0] = pk[nb][2 * mb][0];
                af.u32v[1] = pk[nb][2 * mb][1];
                af.u32v[2] = pk[nb][2 * mb + 1][0];
                af.u32v[3] = pk[nb][2 * mb + 1][1];
                lacc[nb] = __builtin_amdgcn_mfma_f32_16x16x32_bf16(af.v8, ones.v8,
                                                                   lacc[nb], 0, 0, 0);
#pragma unroll
                for (int db = 0; db < 4; ++db)
                    oacc[nb][db] = __builtin_amdgcn_mfma_f32_16x16x32_bf16(af.v8, bfr[db].v8,
                                                                           oacc[nb][db], 0, 0, 0);
            }
        }
        __builtin_amdgcn_s_setprio(0);
    }

    // finalize: O /= l — lacc[nb][r] is l at n = wave*32 + nb*16 + l4*4 + r
#pragma unroll
    for (int nb = 0; nb < 2; ++nb)
#pragma unroll
        for (int r = 0; r < 4; ++r) {
            float inv = 1.f / lacc[nb][r];
            int n = wave * 32 + nb * 16 + l4 * 4 + r;
#pragma unroll
            for (int db = 0; db < 4; ++db) {
                int dd = db * 16 + l15;
                o[((long)(b * 4096 + n0 + n)) * 512 + hh * 64 + dd] = f2bf(oacc[nb][db][r] * inv);
            }
        }
}

extern "C" void kernel_launch(void* const* d_in, const int* in_sizes, int n_in,
                              void* d_out, int out_size, void* d_ws, size_t ws_size,
                              hipStream_t stream) {
    const float* x    = (const float*)d_in[0];
    const float* ctx  = (const float*)d_in[1];
    const float* Wq   = (const float*)d_in[2];
    const float* bq   = (const float*)d_in[3];
    const float* Wk   = (const float*)d_in[4];
    const float* bk   = (const float*)d_in[5];
    const float* Wv   = (const float*)d_in[6];
    const float* bv   = (const float*)d_in[7];
    const float* Wp   = (const float*)d_in[8];
    const float* bp   = (const float*)d_in[9];
    const float* Wsrk = (const float*)d_in[10];
    const float* bsrk = (const float*)d_in[11];
    const float* Wsrv = (const float*)d_in[12];
    const float* bsrv = (const float*)d_in[13];
    const float* gk   = (const float*)d_in[14];
    const float* bek  = (const float*)d_in[15];
    const float* gv   = (const float*)d_in[16];
    const float* bev  = (const float*)d_in[17];

    // workspace layout (elems of bf16)
    ushort_t* x_bf    = (ushort_t*)d_ws;
    ushort_t* ctx_bf  = x_bf    + 16777216;   // contiguous after x_bf
    ushort_t* q_bf    = ctx_bf  + 16777216;
    ushort_t* at_bf   = q_bf    + 16777216;
    ushort_t* k_bf    = at_bf   + 16777216;
    ushort_t* vt_bf   = k_bf    + 4194304;
    ushort_t* convk   = vt_bf   + 4194304;   // LN in-place -> ctx_k
    ushort_t* convv   = convk   + 4194304;   // LN in-place -> ctx_v (contiguous!)
    ushort_t* wq_bf   = convv   + 4194304;   // wq..wp contiguous
    ushort_t* wk_bf   = wq_bf   + 262144;
    ushort_t* wv_bf   = wk_bf   + 262144;
    ushort_t* wp_bf   = wv_bf   + 262144;
    ushort_t* wsrk_p  = wp_bf   + 262144;    // wsrk_p||wsrv_p contiguous
    ushort_t* wsrv_p  = wsrk_p  + 1048576;

    const float EC = 0.18033688011112042f;   // 0.125 * log2(e), folded into q-proj

    // 1) SINGLE prep dispatch: input casts + weight casts + Wsr packing
    prep_all_kernel<<<18944, 256, 0, stream>>>(x, ctx, x_bf,
                                               Wq, Wk, Wv, Wp, wq_bf,
                                               Wsrk, Wsrv, wsrk_p);

    // 2) MERGED: conv-k + conv-v (gather, K=2048) + q-proj (K=512, pre-scaled by EC)
    GemmJob jck = { ctx_bf, wsrk_p, bsrk, convk, 0, 8192,  2048, 1, 1.0f };
    GemmJob jcv = { ctx_bf, wsrv_p, bsrv, convv, 0, 8192,  2048, 1, 1.0f };
    GemmJob jq  = { x_bf,  wq_bf,  bq,   q_bf,  0, 32768, 512,  0, EC };
    gemm_multi<<<1536, 256, 0, stream>>>(jck, jcv, jq, 256, 256);

    // 3) both LayerNorms in one dispatch (convk||convv contiguous)
    ln_kernel<<<4096, 256, 0, stream>>>(convk, gk, bek, gv, bev);

    // 4) k+v projections as dual-job (512 blocks)
    GemmJob jk  = { convk, wk_bf, bk, k_bf,  0, 8192, 512, 0, 1.0f };
    GemmJob jv  = { convv, wv_bf, bv, vt_bf, 2, 8192, 512, 0, 1.0f };
    gemm_multi<<<512, 256, 0, stream>>>(jk, jv, jv, 256, 256);

    // 5) attention: 128 q-rows/block, 2 n-blocks/wave (Q pre-scaled, exp2 direct)
    attn_kernel<<<dim3(32, 8, 8), 256, 0, stream>>>(q_bf, k_bf, vt_bf, at_bf);

    // 6) output projection -> fp32 d_out
    GemmJob jo  = { at_bf, wp_bf, bp, d_out, 1, 32768, 512, 0, 1.0f };
    gemm_multi<<<1024, 256, 0, stream>>>(jo, jo, jo, 1024, 0);
}